// Round 4
// baseline (1326.199 us; speedup 1.0000x reference)
//
#include <hip/hip_runtime.h>

// ConcentrationPredictor: 32 RK4 steps of dc/dt = flux(c), per-cell MLP D_eff.
// R4: wave-autonomous (no barriers in stage loop). Each wave owns a 64-cell
// window, core 48 valid (S_FUSE=2, halo 8/side). Neighbors via __shfl.
// Weights pre-scaled by a prep kernel (scale, 2*log2e, -log2e folded) and
// staged to LDS padded [15][16] for clean ds_read_b128 broadcast.

constexpr int TPB     = 256;
constexpr int S_FUSE  = 2;                  // RK4 steps per launch
constexpr int W_HALO  = 4 * S_FUSE;         // 8 cells/side per wave
constexpr int W_VALID = 64 - 2 * W_HALO;    // 48 valid cells per wave

// d_ws / LDS float layout (rows padded to 16 for b128)
constexpr int O_W1 = 0;     // [15] W1*scale*2log2e
constexpr int O_B1 = 16;    // [15] b1*2log2e
constexpr int O_W2 = 32;    // [15][16] transposed, *2log2e
constexpr int O_B2 = 272;   // [15] *2log2e
constexpr int O_W3 = 288;   // [15][16] transposed, *2log2e
constexpr int O_B3 = 528;   // [15] *2log2e
constexpr int O_W4 = 544;   // [15] *(-log2e)
constexpr int O_B4 = 560;   // [1]  *(-log2e)
constexpr int WTOT = 576;

__device__ __forceinline__ float tanh_pre(float a) {
    // input pre-scaled by 2*log2(e): tanh = 1 - 2/(1+2^a)
    float e = __builtin_amdgcn_exp2f(a);
    return fmaf(-2.0f, __builtin_amdgcn_rcpf(1.0f + e), 1.0f);
}

// prep: scale & transpose weights into d_ws
__global__ __launch_bounds__(256)
void prep_kernel(const float* __restrict__ W1, const float* __restrict__ b1,
                 const float* __restrict__ W2, const float* __restrict__ b2,
                 const float* __restrict__ W3, const float* __restrict__ b3,
                 const float* __restrict__ W4, const float* __restrict__ b4,
                 const float* __restrict__ p_exp, float* __restrict__ ws)
{
    const int tid = threadIdx.x;
    const float K1 = 2.8853900817779268f;   // 2*log2(e)
    const float KS = -1.4426950408889634f;  // -log2(e)
    const float scale = __builtin_amdgcn_exp2f(p_exp[0] * 3.321928094887362f); // 10^p

    for (int i = tid; i < WTOT; i += 256) ws[i] = 0.0f;
    __syncthreads();

    if (tid < 15) {
        ws[O_W1 + tid] = W1[tid] * scale * K1;
        ws[O_B1 + tid] = b1[tid] * K1;
        ws[O_B2 + tid] = b2[tid] * K1;
        ws[O_B3 + tid] = b3[tid] * K1;
        ws[O_W4 + tid] = W4[tid] * KS;
    }
    if (tid == 0) ws[O_B4] = b4[0] * KS;
    if (tid < 225) {
        const int k = tid / 15, j = tid % 15;
        ws[O_W2 + j * 16 + k] = W2[tid] * K1;
        ws[O_W3 + j * 16 + k] = W3[tid] * K1;
    }
}

__global__ __launch_bounds__(TPB)
void rk4_kernel(const float* __restrict__ src,   // state at step s0 [N]
                float* __restrict__ out,         // [T, N]
                const float* __restrict__ t,
                const float* __restrict__ wsrc,  // prescaled weights [WTOT]
                int N, int s0, int nsub)
{
    __shared__ float w[WTOT];
    const int tid = threadIdx.x;
    for (int i = tid; i < WTOT; i += TPB) w[i] = wsrc[i];
    __syncthreads();   // the only barrier

    const int lane = tid & 63;
    const int gw   = blockIdx.x * (TPB / 64) + (tid >> 6);
    const int g    = gw * W_VALID - W_HALO + lane;   // my cell (may be OOB)
    const int gi   = min(max(g, 0), N - 1);

    float c = src[gi];

    // ret(c) with all scaling folded into weights
    auto mret = [&](float x) -> float {
        float h[15], h2[15];
#pragma unroll
        for (int j = 0; j < 15; ++j)
            h[j] = tanh_pre(fmaf(x, w[O_W1 + j], w[O_B1 + j]));
#pragma unroll
        for (int j = 0; j < 15; ++j) {
            float a = w[O_B2 + j];
#pragma unroll
            for (int k = 0; k < 15; ++k) a = fmaf(h[k], w[O_W2 + j * 16 + k], a);
            h2[j] = tanh_pre(a);
        }
#pragma unroll
        for (int j = 0; j < 15; ++j) {
            float a = w[O_B3 + j];
#pragma unroll
            for (int k = 0; k < 15; ++k) a = fmaf(h2[k], w[O_W3 + j * 16 + k], a);
            h[j] = tanh_pre(a);
        }
        float o = w[O_B4];
#pragma unroll
        for (int k = 0; k < 15; ++k) o = fmaf(h[k], w[O_W4 + k], o);
        return __builtin_amdgcn_rcpf(1.0f + __builtin_amdgcn_exp2f(o)); // sigmoid (sign folded)
    };

    // k~ = flux/D0 ; neighbors via wave shuffle (lane edges self-clamp = halo model)
    auto stage = [&](float cc) -> float {
        float cl = __shfl_up(cc, 1);
        float cr = __shfl_down(cc, 1);
        float ret = mret(cc);
        if (g == 0)     return ret * ((1.0f - cc) + (cr - cc));
        if (g == N - 1) { float rbc = 0.0125f * (cl - cc);   // D0*DX
                          return ret * ((cl - cc) + (rbc - cc)); }
        return ret * (cl + cr - 2.0f * cc);
    };

    for (int s = 0; s < nsub; ++s) {
        const float dt = t[s0 + s + 1] - t[s0 + s];
        const float A  = dt * 0.3125f;                 // dt*D0 folded

        float k1 = stage(c);
        float c2 = fmaf(0.5f * A, k1, c);
        float k2 = stage(c2);
        float c3 = fmaf(0.5f * A, k2, c);
        float k3 = stage(c3);
        float c4 = fmaf(A, k3, c);
        float k4 = stage(c4);
        c = fmaf(A * (1.0f / 6.0f), k1 + 2.0f * (k2 + k3) + k4, c);

        if (lane >= W_HALO && lane < W_HALO + W_VALID && (unsigned)g < (unsigned)N)
            out[(size_t)(s0 + s + 1) * N + g] = c;
    }
}

extern "C" void kernel_launch(void* const* d_in, const int* in_sizes, int n_in,
                              void* d_out, int out_size, void* d_ws, size_t ws_size,
                              hipStream_t stream)
{
    const float* c0    = (const float*)d_in[0];
    const float* t     = (const float*)d_in[1];
    const float* W1    = (const float*)d_in[2];
    const float* b1    = (const float*)d_in[3];
    const float* W2    = (const float*)d_in[4];
    const float* b2    = (const float*)d_in[5];
    const float* W3    = (const float*)d_in[6];
    const float* b3    = (const float*)d_in[7];
    const float* W4    = (const float*)d_in[8];
    const float* b4    = (const float*)d_in[9];
    const float* p_exp = (const float*)d_in[10];

    float* out = (float*)d_out;
    float* ws  = (float*)d_ws;

    const int N      = in_sizes[0];       // 65536
    const int nsteps = in_sizes[1] - 1;   // 32

    hipMemcpyAsync(out, c0, (size_t)N * sizeof(float),
                   hipMemcpyDeviceToDevice, stream);

    hipLaunchKernelGGL(prep_kernel, dim3(1), dim3(256), 0, stream,
                       W1, b1, W2, b2, W3, b3, W4, b4, p_exp, ws);

    const int nwaves = (N + W_VALID - 1) / W_VALID;          // 1366
    const int grid   = (nwaves + (TPB / 64) - 1) / (TPB / 64); // 342

    for (int s0 = 0; s0 < nsteps; s0 += S_FUSE) {
        const int nsub = min(S_FUSE, nsteps - s0);
        const float* src = (s0 == 0) ? c0 : out + (size_t)s0 * N;
        hipLaunchKernelGGL(rk4_kernel, dim3(grid), dim3(TPB), 0, stream,
                           src, out, t, ws, N, s0, nsub);
    }
}

// Round 6
// 697.739 us; speedup vs baseline: 1.9007x; 1.9007x over previous
//
#include <hip/hip_runtime.h>

// ConcentrationPredictor: 32 RK4 steps of dc/dt = flux(c), per-cell MLP D_eff.
// R6: interleaved 2-cells/thread (thread holds cells 2L, 2L+1) -> seam-free
// halos using only distance-1 shfl (R4-validated). f32x2 MLP (v_pk_fma_f32),
// pre-scaled weights in LDS, wave-autonomous TPB=64 blocks, no barriers in
// the step loop. unroll-1 + sched_barrier fences pin register pressure.

typedef float f32x2 __attribute__((ext_vector_type(2)));

constexpr int TPB    = 64;                // one wave per block
constexpr int S_FUSE = 4;                 // RK4 steps per launch
constexpr int W_HALO = 4 * S_FUSE;        // 16 cells/side
constexpr int WIN    = 128;               // cells per block (2/thread, interleaved)
constexpr int INNER  = WIN - 2 * W_HALO;  // 96 valid cells per block

// d_ws / LDS float layout (rows padded to 16)
constexpr int O_W1 = 0;     // [15] W1*scale*2log2e
constexpr int O_B1 = 16;    // [15] b1*2log2e
constexpr int O_W2 = 32;    // [15][16] transposed, *2log2e
constexpr int O_B2 = 272;   // [15] *2log2e
constexpr int O_W3 = 288;   // [15][16] transposed, *2log2e
constexpr int O_B3 = 528;   // [15] *2log2e
constexpr int O_W4 = 544;   // [15] *(-log2e)
constexpr int O_B4 = 560;   // [1]  *(-log2e)
constexpr int WTOT = 576;

__device__ __forceinline__ f32x2 pk_fma(f32x2 a, f32x2 b, f32x2 c) {
    return __builtin_elementwise_fma(a, b, c);
}
__device__ __forceinline__ f32x2 splat(float s) { f32x2 v = {s, s}; return v; }

// tanh with input pre-scaled by 2*log2(e): tanh = 1 - 2/(1+2^a)
__device__ __forceinline__ f32x2 tanh_pre2(f32x2 a) {
    f32x2 e, r;
    e.x = __builtin_amdgcn_exp2f(a.x);
    e.y = __builtin_amdgcn_exp2f(a.y);
    r.x = __builtin_amdgcn_rcpf(1.0f + e.x);
    r.y = __builtin_amdgcn_rcpf(1.0f + e.y);
    return pk_fma(splat(-2.0f), r, splat(1.0f));
}

// prep: scale & transpose weights into d_ws (deterministic, runs every call)
__global__ __launch_bounds__(256)
void prep_kernel(const float* __restrict__ W1, const float* __restrict__ b1,
                 const float* __restrict__ W2, const float* __restrict__ b2,
                 const float* __restrict__ W3, const float* __restrict__ b3,
                 const float* __restrict__ W4, const float* __restrict__ b4,
                 const float* __restrict__ p_exp, float* __restrict__ ws)
{
    const int tid = threadIdx.x;
    const float K1 = 2.8853900817779268f;   // 2*log2(e)
    const float KS = -1.4426950408889634f;  // -log2(e)
    const float scale = __builtin_amdgcn_exp2f(p_exp[0] * 3.321928094887362f); // 10^p

    for (int i = tid; i < WTOT; i += 256) ws[i] = 0.0f;
    __syncthreads();

    if (tid < 15) {
        ws[O_W1 + tid] = W1[tid] * scale * K1;
        ws[O_B1 + tid] = b1[tid] * K1;
        ws[O_B2 + tid] = b2[tid] * K1;
        ws[O_B3 + tid] = b3[tid] * K1;
        ws[O_W4 + tid] = W4[tid] * KS;
    }
    if (tid == 0) ws[O_B4] = b4[0] * KS;
    if (tid < 225) {
        const int k = tid / 15, j = tid % 15;
        ws[O_W2 + j * 16 + k] = W2[tid] * K1;
        ws[O_W3 + j * 16 + k] = W3[tid] * K1;
    }
}

__global__ __launch_bounds__(TPB)
void rk4_kernel(const float* __restrict__ src,   // state at step s0 [N]
                float* __restrict__ out,         // [T, N]
                const float* __restrict__ t,
                const float* __restrict__ wsrc,  // prescaled weights [WTOT]
                int N, int s0, int nsub)
{
    __shared__ float w[WTOT];
    const int lane = threadIdx.x;   // TPB == 64, one wave

    for (int i = lane; i < WTOT; i += TPB) w[i] = wsrc[i];
    __syncthreads();

    const int base = blockIdx.x * INNER - W_HALO;   // window start (even)
    const int g0   = base + 2 * lane;               // even cell
    const int g1   = g0 + 1;                        // odd cell

    f32x2 c;
    c.x = src[min(max(g0, 0), N - 1)];
    c.y = src[min(max(g1, 0), N - 1)];

    // MLP ret(c), all scaling folded into pre-scaled weights
    auto mret = [&](f32x2 x) -> f32x2 {
        f32x2 h[15], h2[15];
#pragma unroll
        for (int j = 0; j < 15; ++j)
            h[j] = tanh_pre2(pk_fma(x, splat(w[O_W1 + j]), splat(w[O_B1 + j])));
#pragma unroll
        for (int j = 0; j < 15; ++j) {
            f32x2 a = splat(w[O_B2 + j]);
#pragma unroll
            for (int k = 0; k < 15; ++k)
                a = pk_fma(h[k], splat(w[O_W2 + j * 16 + k]), a);
            h2[j] = tanh_pre2(a);
        }
#pragma unroll
        for (int j = 0; j < 15; ++j) {
            f32x2 a = splat(w[O_B3 + j]);
#pragma unroll
            for (int k = 0; k < 15; ++k)
                a = pk_fma(h2[k], splat(w[O_W3 + j * 16 + k]), a);
            h[j] = tanh_pre2(a);
        }
        f32x2 o = splat(w[O_B4]);
#pragma unroll
        for (int k = 0; k < 15; ++k)
            o = pk_fma(h[k], splat(w[O_W4 + k]), o);
        // sigmoid with sign folded: 1/(1+2^o)
        f32x2 e, r;
        e.x = __builtin_amdgcn_exp2f(o.x);
        e.y = __builtin_amdgcn_exp2f(o.y);
        r.x = __builtin_amdgcn_rcpf(1.0f + e.x);
        r.y = __builtin_amdgcn_rcpf(1.0f + e.y);
        return r;
    };

    // one flux stage, k~ = flux/D0 (D0 folded into dt).
    // Interleaved neighbors: even cell 2L: cl = shfl_up(c.y), cr = c.y;
    //                        odd  cell 2L+1: cl = c.x, cr = shfl_down(c.x).
    // Lane-0 up / lane-63 down self-clamp -> garbage only in halo cells.
    auto stage = [&](f32x2 cc) -> f32x2 {
        float up = __shfl_up(cc.y, 1, 64);    // window[2L-1]
        float dn = __shfl_down(cc.x, 1, 64);  // window[2L+2]
        f32x2 ret = mret(cc);

        float fx, fy;
        if (g0 == 0)                     // N even -> only even comp can be cell 0
            fx = ret.x * ((1.0f - cc.x) + (cc.y - cc.x));
        else
            fx = ret.x * (up + cc.y - 2.0f * cc.x);
        if (g1 == N - 1)                 // N-1 odd -> only odd comp
            fy = ret.y * ((cc.x - cc.y) + (0.0125f * (cc.x - cc.y) - cc.y));
        else
            fy = ret.y * (cc.x + dn - 2.0f * cc.y);
        f32x2 f = {fx, fy};
        return f;
    };

#pragma unroll 1
    for (int s = 0; s < nsub; ++s) {
        const float dt = t[s0 + s + 1] - t[s0 + s];
        const float A  = dt * 0.3125f;                 // dt*D0 folded

        f32x2 k1 = stage(c);
        __builtin_amdgcn_sched_barrier(0);
        f32x2 c2 = pk_fma(splat(0.5f * A), k1, c);
        f32x2 k2 = stage(c2);
        __builtin_amdgcn_sched_barrier(0);
        f32x2 c3 = pk_fma(splat(0.5f * A), k2, c);
        f32x2 k3 = stage(c3);
        __builtin_amdgcn_sched_barrier(0);
        f32x2 c4 = pk_fma(splat(A), k3, c);
        f32x2 k4 = stage(c4);
        __builtin_amdgcn_sched_barrier(0);

        c = pk_fma(splat(A * (1.0f / 6.0f)),
                   k1 + splat(2.0f) * (k2 + k3) + k4, c);

        // valid window [W_HALO, W_HALO+INNER) = [16,112): lanes 8..55 for both comps
        if (lane >= W_HALO / 2 && lane < (W_HALO + INNER) / 2) {
            float* row = out + (size_t)(s0 + s + 1) * N;
            if ((unsigned)g0 < (unsigned)N) row[g0] = c.x;
            if ((unsigned)g1 < (unsigned)N) row[g1] = c.y;
        }
    }
}

extern "C" void kernel_launch(void* const* d_in, const int* in_sizes, int n_in,
                              void* d_out, int out_size, void* d_ws, size_t ws_size,
                              hipStream_t stream)
{
    const float* c0    = (const float*)d_in[0];
    const float* t     = (const float*)d_in[1];
    const float* W1    = (const float*)d_in[2];
    const float* b1    = (const float*)d_in[3];
    const float* W2    = (const float*)d_in[4];
    const float* b2    = (const float*)d_in[5];
    const float* W3    = (const float*)d_in[6];
    const float* b3    = (const float*)d_in[7];
    const float* W4    = (const float*)d_in[8];
    const float* b4    = (const float*)d_in[9];
    const float* p_exp = (const float*)d_in[10];

    float* out = (float*)d_out;
    float* ws  = (float*)d_ws;

    const int N      = in_sizes[0];       // 65536
    const int nsteps = in_sizes[1] - 1;   // 32

    hipMemcpyAsync(out, c0, (size_t)N * sizeof(float),
                   hipMemcpyDeviceToDevice, stream);

    hipLaunchKernelGGL(prep_kernel, dim3(1), dim3(256), 0, stream,
                       W1, b1, W2, b2, W3, b3, W4, b4, p_exp, ws);

    const int grid = (N + INNER - 1) / INNER;   // 683

    for (int s0 = 0; s0 < nsteps; s0 += S_FUSE) {
        const int nsub = min(S_FUSE, nsteps - s0);
        const float* src = (s0 == 0) ? c0 : out + (size_t)s0 * N;
        hipLaunchKernelGGL(rk4_kernel, dim3(grid), dim3(TPB), 0, stream,
                           src, out, t, ws, N, s0, nsub);
    }
}